// Round 1
// baseline (249.159 us; speedup 1.0000x reference)
//
#include <hip/hip_runtime.h>
#include <math.h>

#define NBATCH 8
#define NUM    4096
#define CDIM   1024
#define KP     16        // prototype columns
#define KC     17        // cost columns incl. trash
#define KSTR   20        // padded row stride for K in ws
#define NITER  100
#define FEPS   1e-12f

// ws layout (float offsets)
#define WS_PN  0                          // [8][16][1024] normalized prototypes
#define WS_K   (NBATCH*KP*CDIM)           // [8][4096][20] K matrix
#define WS_NBG (WS_K + NBATCH*NUM*KSTR)   // [8] num_bg per batch
// total ~3.15 MB of ws

// ---------------- kernel A: normalize prototypes + num_bg ----------------
__global__ __launch_bounds__(256) void prep_kernel(
    const float* __restrict__ protos, const int* __restrict__ masks,
    float* __restrict__ ws) {
  float* pn    = ws + WS_PN;
  float* numbg = ws + WS_NBG;
  int bb = blockIdx.x;
  int t = threadIdx.x;
  int w = t >> 6, lane = t & 63;

  // each wave normalizes protos w, w+4, w+8, w+12 (lane owns 16 c-elems)
  #pragma unroll
  for (int pi = 0; pi < 4; ++pi) {
    int p = w + 4 * pi;
    const float* src = protos + ((size_t)(bb * KP + p)) * CDIM + lane * 16;
    float f[16];
    #pragma unroll
    for (int q = 0; q < 4; ++q) {
      float4 v = *(const float4*)(src + 4 * q);
      f[4*q+0] = v.x; f[4*q+1] = v.y; f[4*q+2] = v.z; f[4*q+3] = v.w;
    }
    float ss = 0.f;
    #pragma unroll
    for (int i = 0; i < 16; ++i) ss += f[i] * f[i];
    #pragma unroll
    for (int m = 1; m < 64; m <<= 1) ss += __shfl_xor(ss, m, 64);
    float rn = 1.0f / fmaxf(sqrtf(ss), FEPS);
    float* dst = pn + ((size_t)(bb * KP + p)) * CDIM + lane * 16;
    #pragma unroll
    for (int q = 0; q < 4; ++q) {
      float4 v = make_float4(f[4*q+0]*rn, f[4*q+1]*rn, f[4*q+2]*rn, f[4*q+3]*rn);
      *(float4*)(dst + 4 * q) = v;
    }
  }

  // num_bg = count(masks == 0) per batch
  int cnt = 0;
  for (int i = t; i < NUM; i += 256) cnt += (masks[bb * NUM + i] == 0);
  float c = (float)cnt;
  #pragma unroll
  for (int m = 1; m < 64; m <<= 1) c += __shfl_xor(c, m, 64);
  __shared__ float red[4];
  if (lane == 0) red[w] = c;
  __syncthreads();
  if (t == 0) numbg[bb] = red[0] + red[1] + red[2] + red[3];
}

// ---------------- kernel B: att + K build ----------------
// grid (32, 8), block 512. Block handles 128 rows of one batch.
// Wave pair: even wave -> protos 0..7 (+trash col), odd wave -> protos 8..15.
__global__ __launch_bounds__(512) void attk_kernel(
    const float* __restrict__ feat, const int* __restrict__ masks,
    float* __restrict__ ws) {
  const float* pn = ws + WS_PN;
  float* Kmat = ws + WS_K;
  int bb  = blockIdx.y;
  int grp = blockIdx.x;              // 0..31
  int t = threadIdx.x;
  int w = t >> 6, lane = t & 63;
  int ph   = w & 1;                  // proto half
  int rsub = w >> 1;                 // 0..3

  // per-lane slice of 8 normalized prototypes (c = lane*16 .. +15)
  float pr[8][16];
  #pragma unroll
  for (int pp = 0; pp < 8; ++pp) {
    const float* src = pn + ((size_t)(bb * KP + ph * 8 + pp)) * CDIM + lane * 16;
    #pragma unroll
    for (int q = 0; q < 4; ++q) {
      float4 v = *(const float4*)(src + 4 * q);
      pr[pp][4*q+0] = v.x; pr[pp][4*q+1] = v.y; pr[pp][4*q+2] = v.z; pr[pp][4*q+3] = v.w;
    }
  }

  const float* fb = feat + (size_t)bb * NUM * CDIM;
  float* Kb = Kmat + (size_t)bb * NUM * KSTR;

  for (int i = 0; i < 32; ++i) {
    int n = grp * 128 + rsub + 4 * i;
    const float* fr = fb + (size_t)n * CDIM + lane * 16;
    float f[16];
    #pragma unroll
    for (int q = 0; q < 4; ++q) {
      float4 v = *(const float4*)(fr + 4 * q);
      f[4*q+0] = v.x; f[4*q+1] = v.y; f[4*q+2] = v.z; f[4*q+3] = v.w;
    }
    float ss = 0.f;
    #pragma unroll
    for (int c = 0; c < 16; ++c) ss += f[c] * f[c];
    float d[8];
    #pragma unroll
    for (int pp = 0; pp < 8; ++pp) {
      float acc = 0.f;
      #pragma unroll
      for (int c = 0; c < 16; ++c) acc += f[c] * pr[pp][c];
      d[pp] = acc;
    }
    // butterfly reduce ss + d[0..7] across 64 lanes
    #pragma unroll
    for (int m = 1; m < 64; m <<= 1) {
      ss += __shfl_xor(ss, m, 64);
      #pragma unroll
      for (int pp = 0; pp < 8; ++pp) d[pp] += __shfl_xor(d[pp], m, 64);
    }
    if (lane == 0) {
      float rn = 1.0f / fmaxf(sqrtf(ss), FEPS);
      float kv[8];
      #pragma unroll
      for (int pp = 0; pp < 8; ++pp)
        kv[pp] = expf((d[pp] * rn - 1.0f) * 20.0f);   // exp(-(1-att)/0.05)
      float* dst = Kb + (size_t)n * KSTR + ph * 8;
      *(float4*)(dst + 0) = make_float4(kv[0], kv[1], kv[2], kv[3]);
      *(float4*)(dst + 4) = make_float4(kv[4], kv[5], kv[6], kv[7]);
      if (ph == 0) {
        int mv = masks[bb * NUM + n];
        // exp(-2/0.05) = exp(-40), or exp(0)=1
        Kb[(size_t)n * KSTR + 16] = (mv > 0) ? 4.248354255291589e-18f : 1.0f;
      }
    }
  }
}

// ---------------- kernel C: 100 Sinkhorn iterations + epilogue ----------------
// 8 blocks (one per batch) x 512 threads; thread owns rows t + 512*j, j=0..7;
// K rows live in registers for the whole loop.
__global__ __launch_bounds__(512) void sinkhorn_kernel(
    const float* __restrict__ ws, float* __restrict__ out) {
  const float* Kmat  = ws + WS_K;
  const float* numbg = ws + WS_NBG;
  int bb = blockIdx.x;
  int t = threadIdx.x;
  const float* Kb = Kmat + (size_t)bb * NUM * KSTR;

  float kreg[8][KC];
  #pragma unroll
  for (int j = 0; j < 8; ++j) {
    int n = t + 512 * j;
    const float* kr = Kb + (size_t)n * KSTR;
    #pragma unroll
    for (int q = 0; q < 4; ++q) {
      float4 v = *(const float4*)(kr + 4 * q);
      kreg[j][4*q+0] = v.x; kreg[j][4*q+1] = v.y; kreg[j][4*q+2] = v.z; kreg[j][4*q+3] = v.w;
    }
    kreg[j][16] = kr[16];
  }

  float nbg   = numbg[bb];
  float rowp  = (4096.0f - nbg) * (1.0f / (16.0f * 4096.0f)); // row[k<16]
  float row16 = nbg * (1.0f / 4096.0f);                        // row[16]
  const float col = 1.0f / 4096.0f;

  __shared__ float vlds[KC];
  __shared__ float part[KC][520];
  if (t < KC) vlds[t] = 1.0f;
  __syncthreads();

  float u[8];
  for (int it = 0; it < NITER; ++it) {
    float vr[KC];
    #pragma unroll
    for (int p = 0; p < KC; ++p) vr[p] = vlds[p];
    float s[KC];
    #pragma unroll
    for (int p = 0; p < KC; ++p) s[p] = 0.f;
    #pragma unroll
    for (int j = 0; j < 8; ++j) {
      float dot = 0.f;
      #pragma unroll
      for (int p = 0; p < KC; ++p) dot += kreg[j][p] * vr[p];
      float uu = col * __builtin_amdgcn_rcpf(fmaxf(dot, FEPS));
      u[j] = uu;
      #pragma unroll
      for (int p = 0; p < KC; ++p) s[p] += kreg[j][p] * uu;
    }
    #pragma unroll
    for (int p = 0; p < KC; ++p) part[p][t] = s[p];
    __syncthreads();
    // stage 2: 17 groups x 16 threads sum 512 partials each
    if (t < 272) {
      int k = t >> 4, i = t & 15;
      float acc = 0.f;
      #pragma unroll
      for (int j = 0; j < 32; ++j) acc += part[k][i + 16 * j];
      acc += __shfl_xor(acc, 1, 64);
      acc += __shfl_xor(acc, 2, 64);
      acc += __shfl_xor(acc, 4, 64);
      acc += __shfl_xor(acc, 8, 64);
      if (i == 0) {
        float rw = (k < KP) ? rowp : row16;
        vlds[k] = rw * __builtin_amdgcn_rcpf(fmaxf(acc, FEPS));
      }
    }
    __syncthreads();
  }

  // epilogue: T = u * K * v * 4096, relu, drop trash col
  float vr[KC];
  #pragma unroll
  for (int p = 0; p < KC; ++p) vr[p] = vlds[p];
  float* ob = out + (size_t)bb * NUM * KP;
  #pragma unroll
  for (int j = 0; j < 8; ++j) {
    int n = t + 512 * j;
    float uu = u[j] * 4096.0f;
    float* dst = ob + (size_t)n * KP;
    #pragma unroll
    for (int q = 0; q < 4; ++q) {
      float4 v;
      v.x = fmaxf(uu * kreg[j][4*q+0] * vr[4*q+0], 0.f);
      v.y = fmaxf(uu * kreg[j][4*q+1] * vr[4*q+1], 0.f);
      v.z = fmaxf(uu * kreg[j][4*q+2] * vr[4*q+2], 0.f);
      v.w = fmaxf(uu * kreg[j][4*q+3] * vr[4*q+3], 0.f);
      *(float4*)(dst + 4 * q) = v;
    }
  }
}

extern "C" void kernel_launch(void* const* d_in, const int* in_sizes, int n_in,
                              void* d_out, int out_size, void* d_ws, size_t ws_size,
                              hipStream_t stream) {
  const float* feat   = (const float*)d_in[0];
  const float* protos = (const float*)d_in[1];
  const int*   masks  = (const int*)d_in[2];
  float* out = (float*)d_out;
  float* ws  = (float*)d_ws;

  hipLaunchKernelGGL(prep_kernel, dim3(NBATCH), dim3(256), 0, stream,
                     protos, masks, ws);
  hipLaunchKernelGGL(attk_kernel, dim3(32, NBATCH), dim3(512), 0, stream,
                     feat, masks, ws);
  hipLaunchKernelGGL(sinkhorn_kernel, dim3(NBATCH), dim3(512), 0, stream,
                     ws, out);
}

// Round 2
// 98.811 us; speedup vs baseline: 2.5216x; 2.5216x over previous
//
#include <hip/hip_runtime.h>
#include <math.h>

#define NBATCH 8
#define NUM    4096
#define CDIM   1024
#define KP     16        // prototype columns
#define KC     17        // cost columns incl. trash
#define KSTR   20        // padded row stride for K in ws
#define NITER  100
#define FEPS   1e-12f

// ws layout (float offsets)
#define WS_PN  0                          // [8][16][1024] normalized prototypes
#define WS_K   (NBATCH*KP*CDIM)           // [8][4096][20] K matrix
#define WS_NBG (WS_K + NBATCH*NUM*KSTR)   // [8] num_bg per batch
// total ~3.15 MB of ws

// ---------------- kernel A: normalize prototypes + num_bg ----------------
__global__ __launch_bounds__(256) void prep_kernel(
    const float* __restrict__ protos, const int* __restrict__ masks,
    float* __restrict__ ws) {
  float* pn    = ws + WS_PN;
  float* numbg = ws + WS_NBG;
  int bb = blockIdx.x;
  int t = threadIdx.x;
  int w = t >> 6, lane = t & 63;

  // each wave normalizes protos w, w+4, w+8, w+12 (lane owns 16 c-elems)
  #pragma unroll
  for (int pi = 0; pi < 4; ++pi) {
    int p = w + 4 * pi;
    const float* src = protos + ((size_t)(bb * KP + p)) * CDIM + lane * 16;
    float f[16];
    #pragma unroll
    for (int q = 0; q < 4; ++q) {
      float4 v = *(const float4*)(src + 4 * q);
      f[4*q+0] = v.x; f[4*q+1] = v.y; f[4*q+2] = v.z; f[4*q+3] = v.w;
    }
    float ss = 0.f;
    #pragma unroll
    for (int i = 0; i < 16; ++i) ss += f[i] * f[i];
    #pragma unroll
    for (int m = 1; m < 64; m <<= 1) ss += __shfl_xor(ss, m, 64);
    float rn = 1.0f / fmaxf(sqrtf(ss), FEPS);
    float* dst = pn + ((size_t)(bb * KP + p)) * CDIM + lane * 16;
    #pragma unroll
    for (int q = 0; q < 4; ++q) {
      float4 v = make_float4(f[4*q+0]*rn, f[4*q+1]*rn, f[4*q+2]*rn, f[4*q+3]*rn);
      *(float4*)(dst + 4 * q) = v;
    }
  }

  // num_bg = count(masks == 0) per batch
  int cnt = 0;
  for (int i = t; i < NUM; i += 256) cnt += (masks[bb * NUM + i] == 0);
  float c = (float)cnt;
  #pragma unroll
  for (int m = 1; m < 64; m <<= 1) c += __shfl_xor(c, m, 64);
  __shared__ float red[4];
  if (lane == 0) red[w] = c;
  __syncthreads();
  if (t == 0) numbg[bb] = red[0] + red[1] + red[2] + red[3];
}

// ---------------- kernel B: att + K build ----------------
// grid (32, 8), block 512. Block handles 128 rows of one batch.
// Wave pair: even wave -> protos 0..7 (+trash col), odd wave -> protos 8..15.
// launch_bounds(512,2): 256-VGPR budget so pr[8][16] stays in registers.
__global__ __launch_bounds__(512, 2) void attk_kernel(
    const float* __restrict__ feat, const int* __restrict__ masks,
    float* __restrict__ ws) {
  const float* pn = ws + WS_PN;
  float* Kmat = ws + WS_K;
  int bb  = blockIdx.y;
  int grp = blockIdx.x;              // 0..31
  int t = threadIdx.x;
  int w = t >> 6, lane = t & 63;
  int ph   = w & 1;                  // proto half
  int rsub = w >> 1;                 // 0..3

  // per-lane slice of 8 normalized prototypes (c = lane*16 .. +15)
  float pr[8][16];
  #pragma unroll
  for (int pp = 0; pp < 8; ++pp) {
    const float* src = pn + ((size_t)(bb * KP + ph * 8 + pp)) * CDIM + lane * 16;
    #pragma unroll
    for (int q = 0; q < 4; ++q) {
      float4 v = *(const float4*)(src + 4 * q);
      pr[pp][4*q+0] = v.x; pr[pp][4*q+1] = v.y; pr[pp][4*q+2] = v.z; pr[pp][4*q+3] = v.w;
    }
  }

  const float* fb = feat + (size_t)bb * NUM * CDIM;
  float* Kb = Kmat + (size_t)bb * NUM * KSTR;

  for (int i = 0; i < 32; ++i) {
    int n = grp * 128 + rsub + 4 * i;
    const float* fr = fb + (size_t)n * CDIM + lane * 16;
    float f[16];
    #pragma unroll
    for (int q = 0; q < 4; ++q) {
      float4 v = *(const float4*)(fr + 4 * q);
      f[4*q+0] = v.x; f[4*q+1] = v.y; f[4*q+2] = v.z; f[4*q+3] = v.w;
    }
    float ss = 0.f;
    #pragma unroll
    for (int c = 0; c < 16; ++c) ss += f[c] * f[c];
    float d[8];
    #pragma unroll
    for (int pp = 0; pp < 8; ++pp) {
      float acc = 0.f;
      #pragma unroll
      for (int c = 0; c < 16; ++c) acc += f[c] * pr[pp][c];
      d[pp] = acc;
    }
    // butterfly reduce ss + d[0..7] across 64 lanes
    #pragma unroll
    for (int m = 1; m < 64; m <<= 1) {
      ss += __shfl_xor(ss, m, 64);
      #pragma unroll
      for (int pp = 0; pp < 8; ++pp) d[pp] += __shfl_xor(d[pp], m, 64);
    }
    if (lane == 0) {
      float rn = 1.0f / fmaxf(sqrtf(ss), FEPS);
      float kv[8];
      #pragma unroll
      for (int pp = 0; pp < 8; ++pp)
        kv[pp] = expf((d[pp] * rn - 1.0f) * 20.0f);   // exp(-(1-att)/0.05)
      float* dst = Kb + (size_t)n * KSTR + ph * 8;
      *(float4*)(dst + 0) = make_float4(kv[0], kv[1], kv[2], kv[3]);
      *(float4*)(dst + 4) = make_float4(kv[4], kv[5], kv[6], kv[7]);
      if (ph == 0) {
        int mv = masks[bb * NUM + n];
        // exp(-2/0.05) = exp(-40), or exp(0)=1
        Kb[(size_t)n * KSTR + 16] = (mv > 0) ? 4.248354255291589e-18f : 1.0f;
      }
    }
  }
}

// ---------------- kernel C: 100 Sinkhorn iterations + epilogue ----------------
// 8 blocks (one per batch) x 512 threads; thread owns rows t + 512*j, j=0..7;
// K rows live in registers for the whole loop.
// launch_bounds(512,2): 256-VGPR budget so kreg[8][17] stays in registers
// (round-0 compiled at 88 VGPRs -> whole array spilled to scratch).
__global__ __launch_bounds__(512, 2) void sinkhorn_kernel(
    const float* __restrict__ ws, float* __restrict__ out) {
  const float* Kmat  = ws + WS_K;
  const float* numbg = ws + WS_NBG;
  int bb = blockIdx.x;
  int t = threadIdx.x;
  const float* Kb = Kmat + (size_t)bb * NUM * KSTR;

  float kreg[8][KC];
  #pragma unroll
  for (int j = 0; j < 8; ++j) {
    int n = t + 512 * j;
    const float* kr = Kb + (size_t)n * KSTR;
    #pragma unroll
    for (int q = 0; q < 4; ++q) {
      float4 v = *(const float4*)(kr + 4 * q);
      kreg[j][4*q+0] = v.x; kreg[j][4*q+1] = v.y; kreg[j][4*q+2] = v.z; kreg[j][4*q+3] = v.w;
    }
    kreg[j][16] = kr[16];
  }

  float nbg   = numbg[bb];
  float rowp  = (4096.0f - nbg) * (1.0f / (16.0f * 4096.0f)); // row[k<16]
  float row16 = nbg * (1.0f / 4096.0f);                        // row[16]
  const float col = 1.0f / 4096.0f;

  __shared__ float vlds[KC];
  __shared__ float part[KC][520];
  __shared__ int   flags[2];          // parity-buffered "not converged" flags
  if (t < KC) vlds[t] = 1.0f;
  if (t == 0) { flags[0] = 0; flags[1] = 0; }
  __syncthreads();

  float u[8];
  #pragma unroll 1
  for (int it = 0; it < NITER; ++it) {
    float vr[KC];
    #pragma unroll
    for (int p = 0; p < KC; ++p) vr[p] = vlds[p];
    float s[KC];
    #pragma unroll
    for (int p = 0; p < KC; ++p) s[p] = 0.f;
    #pragma unroll
    for (int j = 0; j < 8; ++j) {
      float dot = 0.f;
      #pragma unroll
      for (int p = 0; p < KC; ++p) dot += kreg[j][p] * vr[p];
      float uu = col * __builtin_amdgcn_rcpf(fmaxf(dot, FEPS));
      u[j] = uu;
      #pragma unroll
      for (int p = 0; p < KC; ++p) s[p] += kreg[j][p] * uu;
    }
    #pragma unroll
    for (int p = 0; p < KC; ++p) part[p][t] = s[p];
    // reset this iteration's flag before barrier1; the only earlier readers
    // of slot (it&1) finished two barriers ago (iter it-2's check).
    if (t == 0) flags[it & 1] = 0;
    __syncthreads();
    // stage 2: 17 groups x 16 threads sum 512 partials each
    if (t < 272) {
      int k = t >> 4, i = t & 15;
      float acc = 0.f;
      #pragma unroll
      for (int j = 0; j < 32; ++j) acc += part[k][i + 16 * j];
      acc += __shfl_xor(acc, 1, 64);
      acc += __shfl_xor(acc, 2, 64);
      acc += __shfl_xor(acc, 4, 64);
      acc += __shfl_xor(acc, 8, 64);
      if (i == 0) {
        float rw = (k < KP) ? rowp : row16;
        float vold = vlds[k];
        float vnew = rw * __builtin_amdgcn_rcpf(fmaxf(acc, FEPS));
        vlds[k] = vnew;
        // benign same-value race: any non-converged k sets the flag to 1
        if (fabsf(vnew - vold) > 1e-6f * fabsf(vnew)) flags[it & 1] = 1;
      }
    }
    __syncthreads();
    if (flags[it & 1] == 0) break;   // converged: remaining ref iters are no-ops
  }

  // epilogue: T = u * K * v * 4096, relu, drop trash col
  float vr[KC];
  #pragma unroll
  for (int p = 0; p < KC; ++p) vr[p] = vlds[p];
  float* ob = out + (size_t)bb * NUM * KP;
  #pragma unroll
  for (int j = 0; j < 8; ++j) {
    int n = t + 512 * j;
    float uu = u[j] * 4096.0f;
    float* dst = ob + (size_t)n * KP;
    #pragma unroll
    for (int q = 0; q < 4; ++q) {
      float4 v;
      v.x = fmaxf(uu * kreg[j][4*q+0] * vr[4*q+0], 0.f);
      v.y = fmaxf(uu * kreg[j][4*q+1] * vr[4*q+1], 0.f);
      v.z = fmaxf(uu * kreg[j][4*q+2] * vr[4*q+2], 0.f);
      v.w = fmaxf(uu * kreg[j][4*q+3] * vr[4*q+3], 0.f);
      *(float4*)(dst + 4 * q) = v;
    }
  }
}

extern "C" void kernel_launch(void* const* d_in, const int* in_sizes, int n_in,
                              void* d_out, int out_size, void* d_ws, size_t ws_size,
                              hipStream_t stream) {
  const float* feat   = (const float*)d_in[0];
  const float* protos = (const float*)d_in[1];
  const int*   masks  = (const int*)d_in[2];
  float* out = (float*)d_out;
  float* ws  = (float*)d_ws;

  hipLaunchKernelGGL(prep_kernel, dim3(NBATCH), dim3(256), 0, stream,
                     protos, masks, ws);
  hipLaunchKernelGGL(attk_kernel, dim3(32, NBATCH), dim3(512), 0, stream,
                     feat, masks, ws);
  hipLaunchKernelGGL(sinkhorn_kernel, dim3(NBATCH), dim3(512), 0, stream,
                     ws, out);
}